// Round 7
// baseline (337.774 us; speedup 1.0000x reference)
//
#include <hip/hip_runtime.h>

// Problem constants (fixed by the reference):
#define NN    40000
#define EE    640000
#define INC   128
#define HID   256
#define OUTC  10
#define GG    64
#define CAP   64        // CSR slot capacity per node (max in-degree << 64 for E/N=16)

typedef unsigned short u16;
typedef __attribute__((ext_vector_type(8))) short short8;   // 8 bf16 (4 VGPRs)
typedef __attribute__((ext_vector_type(4))) float f32x4;    // MFMA acc

__device__ __forceinline__ float bf2f(u16 h) {
    return __uint_as_float(((unsigned)h) << 16);
}
__device__ __forceinline__ u16 f2bf(float f) {   // round-to-nearest-even
    unsigned u = __float_as_uint(f);
    unsigned r = u + 0x7FFFu + ((u >> 16) & 1u);
    return (u16)(r >> 16);
}

// async global->LDS, 16 B per lane (mgemm staging only — R21's gather-to-LDS
// agg FAILED correctness, absmax 0.125; DO NOT RETRY).
__device__ __forceinline__ void gload_lds16(const u16* g, u16* l) {
    __builtin_amdgcn_global_load_lds(
        (const __attribute__((address_space(1))) unsigned int*)g,
        (__attribute__((address_space(3))) unsigned int*)l,
        16, 0, 0);
}

// ---------------------------------------------------------------------------
// build: ONE kernel, two independent segments:
//  [0, e4)       : edge pass — rank = cnt[dst]++ ; col[dst*CAP+rank]=src
//  [e4, e4+WTOT) : weight transpose + bf16 hi/lo split
#define WTOT (INC * HID + HID * HID)
__global__ void build_kernel(const int* __restrict__ src, const int* __restrict__ dst,
                             int* __restrict__ cnt, u16* __restrict__ col, int e4,
                             const float* __restrict__ W1, u16* __restrict__ w1h,
                             u16* __restrict__ w1l,
                             const float* __restrict__ W2, u16* __restrict__ w2h,
                             u16* __restrict__ w2l) {
    int i = blockIdx.x * blockDim.x + threadIdx.x;
    if (i < e4) {
        int4 d = ((const int4*)dst)[i];
        int4 s = ((const int4*)src)[i];
        int r0 = atomicAdd(&cnt[d.x], 1);
        int r1 = atomicAdd(&cnt[d.y], 1);
        int r2 = atomicAdd(&cnt[d.z], 1);
        int r3 = atomicAdd(&cnt[d.w], 1);
        if (r0 < CAP) col[(d.x << 6) + r0] = (u16)s.x;
        if (r1 < CAP) col[(d.y << 6) + r1] = (u16)s.y;
        if (r2 < CAP) col[(d.z << 6) + r2] = (u16)s.z;
        if (r3 < CAP) col[(d.w << 6) + r3] = (u16)s.w;
    } else if (i < e4 + WTOT) {
        int idx = i - e4;
        const float* W; u16 *Th, *Tl; int K;
        if (idx < INC * HID) { W = W1; Th = w1h; Tl = w1l; K = INC; }
        else { W = W2; Th = w2h; Tl = w2l; K = HID; idx -= INC * HID; }
        int k = idx >> 8;          // /256
        int n = idx & 255;
        float w = W[idx];          // idx == k*256 + n (row-major)
        u16 h = f2bf(w);
        float r = w - bf2f(h);
        Th[(size_t)n * K + k] = h;
        Tl[(size_t)n * K + k] = f2bf(r);
    }
}

// ---------------------------------------------------------------------------
// xs = bf16(rsqrt(cnt[n]+1) * x[n]) — pre-scaled features (R22; keeps agg on
// the plain non-PERDIS path). Runs after build (cnt final).
__global__ __launch_bounds__(256) void xscale_kernel(
    const float* __restrict__ x, const int* __restrict__ cnt,
    u16* __restrict__ xs, int total4) {
    int j = blockIdx.x * blockDim.x + threadIdx.x;   // one float4 per thread
    if (j >= total4) return;
    int n = j >> 5;                                  // 32 float4 per 128-row
    float dn = rsqrtf((float)(cnt[n] + 1));
    float4 v = ((const float4*)x)[j];
    ushort4 o;
    o.x = f2bf(v.x * dn); o.y = f2bf(v.y * dn);
    o.z = f2bf(v.z * dn); o.w = f2bf(v.w * dn);
    ((ushort4*)xs)[j] = o;
}

// ---------------------------------------------------------------------------
// MFMA GEMM (R20 PROVEN — do not revert):
// C[M, 256] = A[M,K](bf16) @ (Wh+Wl)[K,256] (W stored transposed [256][K] hi/lo).
//  MODE 0: store bf16(rsqrt(cnt[m]+1)*v) to Cout  (layer 1)
//  MODE 1: accumulate v into pooled[batch[m]][n]  (layer 2 + pool phase 1)
// FAILED, do not retry: R16 BM=64; R19 reg-staged LDS double-buffer.
// Staging: global_load_lds width=16, LINEAR LDS, both-sides 16B-chunk XOR swizzle.
#define BM 128
#define BN 128
#define BK 32
#define PGL 8    // max local graphs per 128-row tile (avg graph = 625 nodes)

template<int MODE>
__global__ __launch_bounds__(256) void mgemm_kernel(
    const u16* __restrict__ A,   // [M,K] bf16
    const u16* __restrict__ Bh,  // [256,K] bf16 (W^T hi)
    const u16* __restrict__ Bl,  // [256,K] bf16 (W^T lo)
    const float* __restrict__ bias,
    const int* __restrict__ cnt,
    u16* __restrict__ Cout,
    const int* __restrict__ batch, float* __restrict__ pooled,
    int M, int K)
{
    __shared__ __align__(16) u16 As [BM * BK];   // 8 KB, linear [row][chunk4]
    __shared__ __align__(16) u16 Bhs[BN * BK];   // 8 KB
    __shared__ __align__(16) u16 Bls[BN * BK];   // 8 KB
    __shared__ float ptile[MODE == 1 ? PGL * BN : 1];   // 4 KB in MODE 1 only

    const int tid  = threadIdx.x;
    const int lane = tid & 63;
    const int wave = tid >> 6;
    const int ln   = lane & 15;        // col within 16x16 tile
    const int qd   = lane >> 4;        // quad: k-unit for A/B frags, row-quad for C
    const int wm   = (wave & 1) * 64;  // wave m-offset in tile
    const int wn   = (wave >> 1) * 64; // wave n-offset in tile
    const int m0   = blockIdx.x * BM;
    const int n0   = blockIdx.y * BN;

    f32x4 acc[4][4];
#pragma unroll
    for (int i = 0; i < 4; ++i)
#pragma unroll
        for (int j = 0; j < 4; ++j) acc[i][j] = (f32x4)(0.0f);

    if (MODE == 1) {
        for (int t = tid; t < PGL * BN; t += 256) ptile[t] = 0.0f;
    }

    // staging lane roles: each wave-load covers 16 rows x 64 B (1 KB LDS)
    const int rl = lane >> 2;          // row within 16-row group
    const int su = lane & 3;           // 16B chunk slot within row
    // frag-read swizzle (uniform across t since wm, t*16 are mult. of 16)
    const int fsw = (qd ^ (ln & 3) ^ ((ln >> 2) & 3)) * 8;

    for (int k0 = 0; k0 < K; k0 += BK) {
        // ---- stage chunk k0: 6 async wave-loads, no VGPR round trip ----
#pragma unroll
        for (int L = 0; L < 2; ++L) {
            int rloc = (wave * 2 + L) * 16 + rl;            // 0..127
            int sw   = (su ^ (rloc & 3) ^ ((rloc >> 2) & 3)) * 8;
            int ga   = m0 + rloc; if (ga >= M) ga = M - 1;  // clamp; rows>=M never read back
            gload_lds16(A  + (size_t)ga * K        + k0 + sw, As  + (size_t)(wave * 2 + L) * 512);
            gload_lds16(Bh + (size_t)(n0 + rloc) * K + k0 + sw, Bhs + (size_t)(wave * 2 + L) * 512);
            gload_lds16(Bl + (size_t)(n0 + rloc) * K + k0 + sw, Bls + (size_t)(wave * 2 + L) * 512);
        }
        __syncthreads();   // drains vmcnt(0): tiles ready

        // ---- fragments + MFMA ----
        short8 af[4], bfh[4], bfl[4];
#pragma unroll
        for (int t = 0; t < 4; ++t) {
            af[t]  = *(const short8*)(As  + (wm + t * 16 + ln) * BK + fsw);
            bfh[t] = *(const short8*)(Bhs + (wn + t * 16 + ln) * BK + fsw);
            bfl[t] = *(const short8*)(Bls + (wn + t * 16 + ln) * BK + fsw);
        }
#pragma unroll
        for (int ti = 0; ti < 4; ++ti)
#pragma unroll
            for (int tj = 0; tj < 4; ++tj) {
                acc[ti][tj] = __builtin_amdgcn_mfma_f32_16x16x32_bf16(
                    af[ti], bfh[tj], acc[ti][tj], 0, 0, 0);
                acc[ti][tj] = __builtin_amdgcn_mfma_f32_16x16x32_bf16(
                    af[ti], bfl[tj], acc[ti][tj], 0, 0, 0);
            }
        __syncthreads();   // frag reads done before next chunk overwrites
    }

    // ---- epilogue: C layout col=lane&15, row=qd*4+reg ----
    float bcol[4];
#pragma unroll
    for (int tj = 0; tj < 4; ++tj) bcol[tj] = bias[n0 + wn + tj * 16 + ln];

    if (MODE == 0) {
#pragma unroll
        for (int ti = 0; ti < 4; ++ti) {
#pragma unroll
            for (int r = 0; r < 4; ++r) {
                int row = m0 + wm + ti * 16 + qd * 4 + r;
                if (row < M) {
                    float dm = rsqrtf((float)(cnt[row] + 1));
                    u16* crow = Cout + (size_t)row * HID;
#pragma unroll
                    for (int tj = 0; tj < 4; ++tj) {
                        float v = fmaxf(acc[ti][tj][r] + bcol[tj], 0.0f);
                        crow[n0 + wn + tj * 16 + ln] = f2bf(v * dm);
                    }
                }
            }
        }
    } else {
        // cache graph ids of this thread's 16 rows
        int bg[16];
#pragma unroll
        for (int ti = 0; ti < 4; ++ti)
#pragma unroll
            for (int r = 0; r < 4; ++r) {
                int row = m0 + wm + ti * 16 + qd * 4 + r;
                bg[ti * 4 + r] = (row < M) ? batch[row] : -1;
            }
        const int g_lo = batch[m0];
        const int g_hi = batch[min(m0 + BM, M) - 1];
        for (int g = g_lo; g <= g_hi; ++g) {
            float cs[4] = {0.0f, 0.0f, 0.0f, 0.0f};
#pragma unroll
            for (int ti = 0; ti < 4; ++ti)
#pragma unroll
                for (int r = 0; r < 4; ++r)
                    if (bg[ti * 4 + r] == g) {
#pragma unroll
                        for (int tj = 0; tj < 4; ++tj)
                            cs[tj] += fmaxf(acc[ti][tj][r] + bcol[tj], 0.0f);
                    }
            // fold the 4 qd lanes holding the same column (lane bits 16, 32)
#pragma unroll
            for (int tj = 0; tj < 4; ++tj) {
                cs[tj] += __shfl_xor(cs[tj], 16);
                cs[tj] += __shfl_xor(cs[tj], 32);
            }
            if (qd == 0) {
                int gl = g - g_lo;
#pragma unroll
                for (int tj = 0; tj < 4; ++tj) {
                    int c = wn + tj * 16 + ln;
                    if (gl < PGL) atomicAdd(&ptile[gl * BN + c], cs[tj]);
                    else atomicAdd(&pooled[(size_t)g * HID + n0 + c], cs[tj]);
                }
            }
        }
        __syncthreads();
        const int g0 = batch[m0];
        for (int t = tid; t < PGL * BN; t += 256) {
            float v = ptile[t];
            if (v != 0.0f) {
                int gl = t / BN, c = t % BN;
                atomicAdd(&pooled[(size_t)(g0 + gl) * HID + n0 + c], v);
            }
        }
    }
}

// ---------------------------------------------------------------------------
// R23: COLUMN-SLICED aggregation, XCD-resident slices.
// Model (corrected after the R1-R6 misread — top-5 only ever showed agg2):
// agg2's FETCH 144 MB = 8 XCDs x 20.5 MB x ~88% — the 20.5 MB h1s working
// set thrashes each 4 MB XCD L2, so every random gather refills over the
// fabric at the measured hard ~3.5 TB/s. Fix footprint, not pipelining:
// split rows into 64 B column slices; dispatch round-robin (blockIdx%8 ->
// XCD, HW-verified by learn_hip m157/m192) pins slice k to XCD k. Per-XCD
// footprint = 40000 x 64 B = 2.56 MB < 4 MB L2 -> rows fetched from L3 once,
// then L2-hit. Slices are independent columns: disjoint outputs, no
// cross-slice reduction. Wave layout: gi=lane>>2 (16 item slots), li=lane&3
// (16 B sub-slice); one gather instr covers 16 items; 4 nodes unrolled/wave.
// REVERT CRITERION (pre-committed): if agg dur rises / FETCH ~300 MB, the %8
// mapping is wrong -> restore R22 agg next round.
// Prior failed/neutral (old structure — do not retry): R8 UFx2, R10 2-waves/
// node, R13 src-partition, R19 shfl-hoist, R21 gather-to-LDS (broken).
template<int F>
__global__ __launch_bounds__(256) void agg_kernel(
    const u16* __restrict__ hs, const int* __restrict__ cnt,
    const u16* __restrict__ col, u16* __restrict__ out, int n_nodes)
{
    constexpr int NSL = F / 32;              // 64 B slices per row (4 or 8)
    const int tid  = threadIdx.x;
    const int lane = tid & 63;
    const int wave = tid >> 6;
    const int gi   = lane >> 2;              // item slot 0..15
    const int li   = lane & 3;               // 16 B sub-slice 0..3
    const int virt  = blockIdx.x & 7;        // == XCD id (round-robin dispatch)
    const int slice = virt % NSL;            // XCD k -> slice k%NSL only
    const int nchunk = (blockIdx.x >> 3) * (8 / NSL) + virt / NSL;
    const int nb = nchunk * 16 + wave * 4;   // this wave's 4 nodes

    int cn[4];
#pragma unroll
    for (int u = 0; u < 4; ++u) cn[u] = cnt[nb + u];
    const int tmax = max(max(cn[0], cn[1]), max(cn[2], cn[3])) + 1;

    float acc[4][8];
#pragma unroll
    for (int u = 0; u < 4; ++u)
#pragma unroll
        for (int i = 0; i < 8; ++i) acc[u][i] = 0.0f;

    const u16* hsl = hs + slice * 32 + li * 8;   // lane's 16 B within any row

    for (int base = 0; base < tmax; base += 16) {
        const int it = base + gi;            // item id: 0=self, 1..cn=edges
        // phase 1: 4 independent index fetches (clamped; masked later)
        int idx[4]; bool val[4];
#pragma unroll
        for (int u = 0; u < 4; ++u) {
            val[u] = (it <= cn[u]);
            int ci = ((nb + u) << 6) + min(max(it - 1, 0), 63);
            int v  = (it == 0) ? (nb + u) : (int)col[ci];
            idx[u] = val[u] ? v : (nb + u);
        }
        // phase 2: 4 independent gathers (each: 16 items x 64 B, 1 KB/instr)
        uint4 g[4];
#pragma unroll
        for (int u = 0; u < 4; ++u)
            g[u] = *(const uint4*)(hsl + (size_t)idx[u] * F);
        // phase 3: masked accumulate
#pragma unroll
        for (int u = 0; u < 4; ++u)
            if (val[u]) {
                unsigned uu[4] = {g[u].x, g[u].y, g[u].z, g[u].w};
#pragma unroll
                for (int q = 0; q < 4; ++q) {
                    acc[u][2 * q]     += __uint_as_float(uu[q] << 16);
                    acc[u][2 * q + 1] += __uint_as_float(uu[q] & 0xFFFF0000u);
                }
            }
    }

    // fold the 16 item slots (lane bits 2..5); lanes sharing li get the sum
#pragma unroll
    for (int u = 0; u < 4; ++u)
#pragma unroll
        for (int off = 4; off <= 32; off <<= 1)
#pragma unroll
            for (int i = 0; i < 8; ++i)
                acc[u][i] += __shfl_xor(acc[u][i], off);

    if (gi == 0) {       // lanes 0..3 = li slots: 4 x 16 B = the 64 B slice
#pragma unroll
        for (int u = 0; u < 4; ++u) {
            float dn = rsqrtf((float)(cn[u] + 1));
            uint4 r;
            r.x = (unsigned)f2bf(acc[u][0] * dn) | ((unsigned)f2bf(acc[u][1] * dn) << 16);
            r.y = (unsigned)f2bf(acc[u][2] * dn) | ((unsigned)f2bf(acc[u][3] * dn) << 16);
            r.z = (unsigned)f2bf(acc[u][4] * dn) | ((unsigned)f2bf(acc[u][5] * dn) << 16);
            r.w = (unsigned)f2bf(acc[u][6] * dn) | ((unsigned)f2bf(acc[u][7] * dn) << 16);
            *(uint4*)(out + (size_t)(nb + u) * F + slice * 32 + li * 8) = r;
        }
    }
}

// ---------------------------------------------------------------------------
// Pool finalize: divide pooled sums by counts (binary search on sorted batch)
// + final linear.  (Pool phase 1 lives in mgemm<1>'s epilogue.)
__global__ __launch_bounds__(256) void pool_finalize_kernel(
    const float* __restrict__ pooled, const int* __restrict__ batch,
    const float* __restrict__ Wlin, const float* __restrict__ blin,
    float* __restrict__ out, int n_nodes)
{
    const int g = blockIdx.x;
    const int j = threadIdx.x;
    int lo = 0, hi = n_nodes;
    while (lo < hi) { int mid = (lo + hi) >> 1; if (batch[mid] < g) lo = mid + 1; else hi = mid; }
    const int start = lo;
    lo = start; hi = n_nodes;
    while (lo < hi) { int mid = (lo + hi) >> 1; if (batch[mid] < g + 1) lo = mid + 1; else hi = mid; }
    const int cnt = lo - start;

    float pv = pooled[(size_t)g * HID + j] / fmaxf((float)cnt, 1.0f);

    __shared__ float pl[HID];
    pl[j] = pv;
    __syncthreads();
    if (j < OUTC) {
        float o = blin[j];
        for (int k = 0; k < HID; ++k) o = fmaf(pl[k], Wlin[k * OUTC + j], o);
        out[g * OUTC + j] = o;
    }
}

// ---------------------------------------------------------------------------
extern "C" void kernel_launch(void* const* d_in, const int* in_sizes, int n_in,
                              void* d_out, int out_size, void* d_ws, size_t ws_size,
                              hipStream_t stream) {
    const float* x     = (const float*)d_in[0];
    const int*   ei    = (const int*)  d_in[1];   // [2, E]: row0 src, row1 dst
    const int*   batch = (const int*)  d_in[2];
    const float* W1    = (const float*)d_in[3];
    const float* b1    = (const float*)d_in[4];
    const float* W2    = (const float*)d_in[5];
    const float* b2    = (const float*)d_in[6];
    const float* Wlin  = (const float*)d_in[7];
    const float* blin  = (const float*)d_in[8];
    float* out = (float*)d_out;

    const int* src = ei;
    const int* dst = ei + EE;

    // workspace layout. [pooled|cnt] contiguous -> zeroed by one hipMemsetAsync.
    char* p = (char*)d_ws;
    u16*   xs  = (u16*)p;   p += (size_t)NN * INC * sizeof(u16);    // 10.24 MB
    u16*   xab = (u16*)p;   p += (size_t)NN * INC * sizeof(u16);    // 10.24 MB
    u16*   h1s = (u16*)p;   p += (size_t)NN * HID * sizeof(u16);    // 20.48 MB
    u16*   a2b = (u16*)p;   p += (size_t)NN * HID * sizeof(u16);    // 20.48 MB
    u16*   w1h = (u16*)p;   p += (size_t)HID * INC * sizeof(u16);
    u16*   w1l = (u16*)p;   p += (size_t)HID * INC * sizeof(u16);
    u16*   w2h = (u16*)p;   p += (size_t)HID * HID * sizeof(u16);
    u16*   w2l = (u16*)p;   p += (size_t)HID * HID * sizeof(u16);
    char* zbase = p;                                         // memset region:
    float* pooled = (float*)p; p += (size_t)GG * HID * sizeof(float); //  pooled
    int* cnt    = (int*)p;  p += (size_t)NN * sizeof(int);            //  cnt
    size_t zbytes = (size_t)(p - zbase);
    u16* col    = (u16*)p;  p += (size_t)NN * CAP * sizeof(u16);      // 5.12 MB
    (void)ws_size; (void)n_in; (void)in_sizes; (void)out_size;

    const int TB = 256;
    const int e4     = EE / 4;                  // EE divisible by 4
    const int total4 = NN * INC / 4;
    const int build_threads = e4 + WTOT;
    const int nb_build = (build_threads + TB - 1) / TB;

    // structure pass (rebuilt every call; ws re-poisoned)
    hipMemsetAsync(zbase, 0, zbytes, stream);
    build_kernel<<<nb_build, TB, 0, stream>>>(src, dst, cnt, col, e4,
                                              W1, w1h, w1l, W2, w2h, w2l);
    // pre-scaled features (needs final cnt)
    xscale_kernel<<<(total4 + TB - 1) / TB, TB, 0, stream>>>(x, cnt, xs, total4);

    dim3 ggrid((NN + BM - 1) / BM, HID / BN);   // 313 x 2 blocks
    // sliced agg grids: (NN/16 node-chunks) x NSL slices, 16 nodes per block
    const int agg1_blocks = (NN / 16) * (INC / 32);   // 2500 x 4 = 10000
    const int agg2_blocks = (NN / 16) * (HID / 32);   // 2500 x 8 = 20000

    // layer 1: xab = bf16(d_n .* sum xs[idx]); h1s = bf16(d_m .* relu(xab@W1 + b1))
    agg_kernel<INC><<<agg1_blocks, TB, 0, stream>>>(xs, cnt, col, xab, NN);
    mgemm_kernel<0><<<ggrid, 256, 0, stream>>>(xab, w1h, w1l, b1, cnt, h1s,
                                               batch, pooled, NN, INC);

    // layer 2: a2b = bf16(d_n .* (h1s self + gather));
    // gemm2 fuses relu(a2b@W2 + b2) with pool phase 1 (conflict-free reduction)
    agg_kernel<HID><<<agg2_blocks, TB, 0, stream>>>(h1s, cnt, col, a2b, NN);
    mgemm_kernel<1><<<ggrid, 256, 0, stream>>>(a2b, w2h, w2l, b2, cnt, (u16*)nullptr,
                                               batch, pooled, NN, HID);

    // pool finalize (divide by counts) + linear
    pool_finalize_kernel<<<GG, 256, 0, stream>>>(pooled, batch, Wlin, blin, out, NN);
}